// Round 21
// baseline (206.720 us; speedup 1.0000x reference)
//
#include <hip/hip_runtime.h>
#include <hip/hip_bf16.h>
#include <math.h>

#define N_NODES 32000
#define NUM_GRAPHS 32
#define NPG 1000
#define N_EDGES 256000
#define IN_DIM 1024
#define HID 256
#define NW 528    // C width: 256 (Wl1) + 256 (Wr1) + 8 (Wla) + 8 (Wra)
#define KBH 1040  // LDS halves-stride per kb-block: 128*8 + 16 pad (2080 B)
#define WS_KS 16896  // WsT2 halves per K=32 step: 4*4096 + 512
#define ZWORDS 75776 // prep-zeroed scratch: Xp 65536 + Ap 2048 + Hacc 8192 (deg/cursor via memset)

typedef _Float16 half8 __attribute__((ext_vector_type(8)));
typedef _Float16 half4 __attribute__((ext_vector_type(4)));
typedef float f32x4 __attribute__((ext_vector_type(4)));

__device__ __forceinline__ void gload16(const void* g, void* l) {
  __builtin_amdgcn_global_load_lds((const __attribute__((address_space(1))) void*)g,
                                   (__attribute__((address_space(3))) void*)l, 16, 0, 0);
}

// ---------------- prep_all: xhalf + W-convert + count_deg + zero scratch, one launch ----------------
// grid 16512 x 256. bid<16000: XH = fp16(x) (8 elem/thread). 16000..16383: W-convert
// (fb = bid-16000: kslot = fb/3, n = (fb%3)*256+t). >=16384: count_deg (2000 edges/block).
// First 512 blocks also zero Xp/Ap/Hacc. deg/cursor zeroed by prior hipMemsetAsync.
__global__ __launch_bounds__(256) void prep_all(
    const float* __restrict__ Wl1, const float* __restrict__ Wr1,
    const float* __restrict__ Wla, const float* __restrict__ Wra,
    const float* __restrict__ x, _Float16* __restrict__ WsT2,
    _Float16* __restrict__ XH, unsigned* __restrict__ zbuf,
    const int* __restrict__ dst, int* __restrict__ deg)
{
  const int bid = blockIdx.x;
  const int t = threadIdx.x;
  if (bid < 512) {
    for (int i = bid * 256 + t; i < ZWORDS; i += 512 * 256) zbuf[i] = 0u;
  }

  if (bid < 16000) {
    const size_t i = ((size_t)bid * 256 + t) * 8;
    float4 a = *(const float4*)(x + i);
    float4 b = *(const float4*)(x + i + 4);
    half8 h;
    h[0] = (_Float16)a.x; h[1] = (_Float16)a.y; h[2] = (_Float16)a.z; h[3] = (_Float16)a.w;
    h[4] = (_Float16)b.x; h[5] = (_Float16)b.y; h[6] = (_Float16)b.z; h[7] = (_Float16)b.w;
    *(half8*)&XH[i] = h;
    return;
  }
  if (bid >= 16384) {
    const int e0 = (bid - 16384) * 2000;
    for (int i = t; i < 2000; i += 256) atomicAdd(&deg[dst[e0 + i]], 1);
    return;
  }

  const int fb = bid - 16000;          // 0..383
  const int kslot = fb / 3;            // 0..127 -> k0 = kslot*8
  const int n = (fb % 3) * 256 + t;
  if (n >= NW) return;
  const int k0 = kslot * 8;
  half8 o;
#pragma unroll
  for (int i = 0; i < 8; ++i) {
    const int k = k0 + i;
    float v;
    if (n < 256)      v = Wl1[(size_t)k * 256 + n];
    else if (n < 512) v = Wr1[(size_t)k * 256 + n - 256];
    else if (n < 520) v = Wla[(size_t)k * 8 + n - 512];
    else              v = Wra[(size_t)k * 8 + n - 520];
    o[i] = (_Float16)v;
  }
  const int K = kslot >> 2, kb = kslot & 3;
  size_t off;
  if (n < 512) off = (size_t)K * WS_KS + (size_t)(n >> 7) * 4096 + kb * 1024 + (n & 127) * 8;
  else         off = (size_t)K * WS_KS + 16384 + (kb * 128) + (n - 512) * 8;
  *(half8*)&WsT2[off] = o;
}

// ---------------- MFMA GEMM (R14 structure, 72.5 us proven) + embedded scan ----------------
// Blocks 0..1249: C[32000,528](fp16) = XH @ fp16([Wl1|Wr1|Wla|Wra]). BM=128, BN=128, BK=32,
// single-buffer LDS 16.6 KB. Block 1250: CSR prefix scan (deg -> offsets).
__global__ __launch_bounds__(256) void gemm_mfma(
    const _Float16* __restrict__ XH, const _Float16* __restrict__ WsT2,
    _Float16* __restrict__ C, const int* __restrict__ deg, int* __restrict__ offsets)
{
  __shared__ _Float16 AH[4 * KBH];
  __shared__ _Float16 Bs[4 * KBH];

  const int orig = blockIdx.x;
  const int tid = threadIdx.x;

  if (orig == 1250) {
    // ---- scan block: 256 threads x 125 nodes, two-pass ----
    int* part = (int*)AH;
    const int base = tid * 125;
    int s = 0;
    for (int i = 0; i < 125; ++i) s += deg[base + i];
    part[tid] = s;
    __syncthreads();
    for (int off = 1; off < 256; off <<= 1) {
      int v = (tid >= off) ? part[tid - off] : 0;
      __syncthreads();
      part[tid] += v;
      __syncthreads();
    }
    int run = part[tid] - s;   // exclusive prefix
    for (int i = 0; i < 125; ++i) {
      offsets[base + i] = run;
      run += deg[base + i];
    }
    if (tid == 255) offsets[N_NODES] = part[255];
    return;
  }

  const int xcd = orig & 7, idx = orig >> 3;
  // bijective XCD swizzle, nwg=1250: q=156, r=2
  const int g = (xcd < 2 ? xcd * 157 : 314 + (xcd - 2) * 156) + idx;
  const int pm = g / 5, nb = g % 5;
  const int m0 = pm * 128;

  const int w = tid >> 6, l = tid & 63;
  const int wr = w >> 1, wc = w & 1;
  const int r16 = l & 15, kb4 = l >> 4;

  // staging maps: chunk c = tid + j*256 (j<2): kb = c>>7 (0..3), row/col = c&127
  int lpA[2];
  const _Float16* gA[2];
  const _Float16* gB[2];
#pragma unroll
  for (int j = 0; j < 2; ++j) {
    const int c = tid + j * 256;
    const int kb = c >> 7, row = c & 127;
    lpA[j] = kb * KBH + row * 8;
    gA[j] = XH + (size_t)(m0 + row) * IN_DIM + kb * 8;
    gB[j] = WsT2 + nb * 4096 + (size_t)c * 8;   // valid for nb<4
  }

  if (nb < 4) {
    f32x4 acc[4][4] = {};
    for (int ks = 0; ks < 32; ++ks) {
      const size_t ko = (size_t)ks * 32;
      const size_t bo = (size_t)ks * WS_KS;
      __syncthreads();
      gload16(gA[0] + ko, &AH[lpA[0]]);
      gload16(gA[1] + ko, &AH[lpA[1]]);
      gload16(gB[0] + bo, &Bs[lpA[0]]);
      gload16(gB[1] + bo, &Bs[lpA[1]]);
      __syncthreads();

      half8 bf[4];
#pragma unroll
      for (int n = 0; n < 4; ++n)
        bf[n] = *(half8*)&Bs[kb4 * KBH + (wc * 64 + n * 16 + r16) * 8];
#pragma unroll
      for (int m = 0; m < 4; ++m) {
        half8 ah = *(half8*)&AH[kb4 * KBH + (wr * 64 + m * 16 + r16) * 8];
#pragma unroll
        for (int n = 0; n < 4; ++n)
          acc[m][n] = __builtin_amdgcn_mfma_f32_16x16x32_f16(ah, bf[n], acc[m][n], 0, 0, 0);
      }
    }

    const int crow0 = m0 + wr * 64 + ((l >> 4) << 2);
    const int ccol0 = nb * 128 + wc * 64 + r16;
#pragma unroll
    for (int m = 0; m < 4; ++m)
#pragma unroll
      for (int n = 0; n < 4; ++n)
#pragma unroll
        for (int r = 0; r < 4; ++r)
          C[(size_t)(crow0 + m * 16 + r) * NW + ccol0 + n * 16] = (_Float16)acc[m][n][r];
  } else {
    // SP block: 16 cols (512..527); single buffer.
    f32x4 acc2[2] = {};
    for (int ks = 0; ks < 32; ++ks) {
      const size_t ko = (size_t)ks * 32;
      const size_t bo = (size_t)ks * WS_KS + 16384;
      __syncthreads();
      gload16(gA[0] + ko, &AH[lpA[0]]);
      gload16(gA[1] + ko, &AH[lpA[1]]);
      if (tid < 64) gload16(WsT2 + bo + tid * 8, &Bs[tid * 8]);
      __syncthreads();

      half8 bf = *(half8*)&Bs[(kb4 * 16 + r16) * 8];
#pragma unroll
      for (int m = 0; m < 2; ++m) {
        half8 ah = *(half8*)&AH[kb4 * KBH + (w * 32 + m * 16 + r16) * 8];
        acc2[m] = __builtin_amdgcn_mfma_f32_16x16x32_f16(ah, bf, acc2[m], 0, 0, 0);
      }
    }
    const int crow0 = m0 + w * 32 + ((l >> 4) << 2);
    const int ccol0 = 512 + r16;
#pragma unroll
    for (int m = 0; m < 2; ++m)
#pragma unroll
      for (int r = 0; r < 4; ++r)
        C[(size_t)(crow0 + m * 16 + r) * NW + ccol0] = (_Float16)acc2[m][r];
  }
}

__global__ void scatter_kernel(const int* __restrict__ src, const int* __restrict__ dst,
                               const int* __restrict__ offsets, int* __restrict__ cursor,
                               int* __restrict__ srcSorted) {
  int e = blockIdx.x * blockDim.x + threadIdx.x;
  if (e < N_EDGES) {
    int d = dst[e];
    int pos = offsets[d] + atomicAdd(&cursor[d], 1);
    srcSorted[pos] = src[e];
  }
}

// ---------------- per-node aggregation: wave-per-node, vectorized gathers ----------------
__global__ __launch_bounds__(256) void aggregate_node(
    const _Float16* __restrict__ C,
    const int* __restrict__ offsets, const int* __restrict__ srcSorted,
    const float* __restrict__ bl1, const float* __restrict__ bla,
    _Float16* __restrict__ Zh, float* __restrict__ Ss)
{
  const int bid = blockIdx.x;
  const int wv = threadIdx.x >> 6, lane = threadIdx.x & 63;
  const int node = (bid & 7) * 4000 + (bid >> 3) * 4 + wv;  // graphs pinned to XCDs
  const int b = offsets[node], e = offsets[node + 1];
  const int cnt = e - b;
  const float4 blv = *(const float4*)(bl1 + 4 * lane);
  float a0 = 0.f, a1 = 0.f, a2 = 0.f, a3 = 0.f, sp = 0.f;
  int p = b;
  int sNext = (p < e) ? srcSorted[p] : 0;
  while (p < e) {
    const int s = sNext;
    ++p;
    sNext = (p < e) ? srcSorted[p] : 0;   // prefetch next index
    const _Float16* row = C + (size_t)s * NW;
    half4 v = *(const half4*)(row + 4 * lane);
    float spv = 0.f;
    if (lane < 8) spv = (float)row[512 + lane];
    a0 += (float)v[0]; a1 += (float)v[1]; a2 += (float)v[2]; a3 += (float)v[3];
    sp += spv;
  }
  const float inv = (cnt > 0) ? 1.f / (float)cnt : 0.f;
  const _Float16* self = C + (size_t)node * NW;
  half4 sv = *(const half4*)(self + 256 + 4 * lane);
  half4 zo;
  zo[0] = (_Float16)fmaxf(a0 * inv + blv.x + (float)sv[0], 0.f);
  zo[1] = (_Float16)fmaxf(a1 * inv + blv.y + (float)sv[1], 0.f);
  zo[2] = (_Float16)fmaxf(a2 * inv + blv.z + (float)sv[2], 0.f);
  zo[3] = (_Float16)fmaxf(a3 * inv + blv.w + (float)sv[3], 0.f);
  *(half4*)(Zh + (size_t)node * 256 + 4 * lane) = zo;

  float sval = 0.f;
  if (lane < 8) sval = sp * inv + bla[lane] + (float)self[520 + lane];
  float m = sval;
  m = fmaxf(m, __shfl_xor(m, 1));
  m = fmaxf(m, __shfl_xor(m, 2));
  m = fmaxf(m, __shfl_xor(m, 4));
  float ex = expf(sval - m);
  float su = ex;
  su += __shfl_xor(su, 1);
  su += __shfl_xor(su, 2);
  su += __shfl_xor(su, 4);
  if (lane < 8) Ss[(size_t)node * 8 + lane] = ex / su;
}

// ---------------- pool: per 125-node chunk: AggS (LDS) -> Ap partial + Xp partial ----------------
__global__ __launch_bounds__(256) void pool_kernel(
    const float* __restrict__ Ss, const _Float16* __restrict__ Zh,
    const int* __restrict__ offsets, const int* __restrict__ srcSorted,
    float* __restrict__ Xp, float* __restrict__ Ap)
{
  const int g = blockIdx.x >> 3;
  const int chunk = blockIdx.x & 7;
  const int n0 = g * NPG + chunk * 125;
  const int t = threadIdx.x;
  __shared__ float lSs[125][8];
  __shared__ float lAg[125][8];
  __shared__ float apTmp[4][64];

  if (t < 125) {
    const int node = n0 + t;
    float4 s0 = *(const float4*)&Ss[(size_t)node * 8];
    float4 s1 = *(const float4*)&Ss[(size_t)node * 8 + 4];
    lSs[t][0] = s0.x; lSs[t][1] = s0.y; lSs[t][2] = s0.z; lSs[t][3] = s0.w;
    lSs[t][4] = s1.x; lSs[t][5] = s1.y; lSs[t][6] = s1.z; lSs[t][7] = s1.w;
    float a[8] = {0.f, 0.f, 0.f, 0.f, 0.f, 0.f, 0.f, 0.f};
    const int b = offsets[node], e = offsets[node + 1];
    for (int p = b; p < e; ++p) {
      const int s = srcSorted[p];
      float4 v0 = *(const float4*)&Ss[(size_t)s * 8];
      float4 v1 = *(const float4*)&Ss[(size_t)s * 8 + 4];
      a[0] += v0.x; a[1] += v0.y; a[2] += v0.z; a[3] += v0.w;
      a[4] += v1.x; a[5] += v1.y; a[6] += v1.z; a[7] += v1.w;
    }
#pragma unroll
    for (int c = 0; c < 8; ++c) lAg[t][c] = a[c];
  }
  __syncthreads();
  {
    const int sl = t >> 6, i = (t >> 3) & 7, j = t & 7;
    float acc = 0.f;
    for (int n = sl; n < 125; n += 4) acc += lAg[n][i] * lSs[n][j];
    apTmp[sl][((i << 3) | j)] = acc;
  }
  __syncthreads();
  if (t < 64) atomicAdd(&Ap[g * 64 + t], apTmp[0][t] + apTmp[1][t] + apTmp[2][t] + apTmp[3][t]);
  float xc[8] = {0.f, 0.f, 0.f, 0.f, 0.f, 0.f, 0.f, 0.f};
  for (int n = 0; n < 125; ++n) {
    float zv = (float)Zh[(size_t)(n0 + n) * 256 + t];
#pragma unroll
    for (int c = 0; c < 8; ++c) xc[c] = fmaf(lSs[n][c], zv, xc[c]);
  }
#pragma unroll
  for (int c = 0; c < 8; ++c)
    atomicAdd(&Xp[((size_t)g * 8 + c) * 256 + t], xc[c]);
}

// ---------------- zpcls: per (g,j) pooled node: agg -> Zp row -> Wc1 partial -> Hacc ----------------
__global__ __launch_bounds__(256) void zpcls_kernel(
    const float* __restrict__ Xp, const float* __restrict__ Ap,
    const float* __restrict__ Wl2, const float* __restrict__ bl2,
    const float* __restrict__ Wr2, const float* __restrict__ Wc1,
    float* __restrict__ Hacc)
{
  const int g = blockIdx.x >> 3;
  const int j = blockIdx.x & 7;
  const int c = threadIdx.x;
  __shared__ float lXp[8][256];
  __shared__ float agg[256];
  __shared__ float zrow[256];
  __shared__ float lAp[64];
#pragma unroll
  for (int i = 0; i < 8; ++i) lXp[i][c] = Xp[((size_t)g * 8 + i) * 256 + c];
  if (c < 64) lAp[c] = Ap[g * 64 + c];
  __syncthreads();
  {
    float d = 0.f, s = 0.f;
#pragma unroll
    for (int i = 0; i < 8; ++i) {
      bool m = (lAp[i * 8 + j] != 0.f);
      d += m ? 1.f : 0.f;
      s += m ? lXp[i][c] : 0.f;
    }
    agg[c] = (d > 0.f) ? s / fmaxf(d, 1.f) : 0.f;
  }
  __syncthreads();
  float az = bl2[c];
#pragma unroll 8
  for (int k = 0; k < 256; ++k)
    az += agg[k] * Wl2[(size_t)k * 256 + c] + lXp[j][k] * Wr2[(size_t)k * 256 + c];
  zrow[c] = fmaxf(az, 0.f);
  __syncthreads();
  float h = 0.f;
  const float* wc1 = Wc1 + (size_t)(j * 256) * 256 + c;
#pragma unroll 8
  for (int k = 0; k < 256; ++k)
    h = fmaf(zrow[k], wc1[(size_t)k * 256], h);
  atomicAdd(&Hacc[g * 256 + c], h);
}

// ---------------- out: out[g] = bc2 + sum_c relu(Hacc+bc1)*Wc2 ----------------
__global__ __launch_bounds__(256) void out_kernel(
    const float* __restrict__ Hacc, const float* __restrict__ bc1,
    const float* __restrict__ Wc2, const float* __restrict__ bc2,
    float* __restrict__ out)
{
  const int g = blockIdx.x;
  const int t = threadIdx.x;
  __shared__ float red[256];
  red[t] = fmaxf(Hacc[g * 256 + t] + bc1[t], 0.f) * Wc2[t];
  __syncthreads();
  for (int off = 128; off > 0; off >>= 1) {
    if (t < off) red[t] += red[t + off];
    __syncthreads();
  }
  if (t == 0) out[g] = red[0] + bc2[0];
}

extern "C" void kernel_launch(void* const* d_in, const int* in_sizes, int n_in,
                              void* d_out, int out_size, void* d_ws, size_t ws_size,
                              hipStream_t stream) {
  const float* x   = (const float*)d_in[0];
  const int*   ei  = (const int*)d_in[1];
  const float* Wl1 = (const float*)d_in[3];
  const float* bl1 = (const float*)d_in[4];
  const float* Wr1 = (const float*)d_in[5];
  const float* Wla = (const float*)d_in[6];
  const float* bla = (const float*)d_in[7];
  const float* Wra = (const float*)d_in[8];
  const float* Wl2 = (const float*)d_in[9];
  const float* bl2 = (const float*)d_in[10];
  const float* Wr2 = (const float*)d_in[11];
  const float* Wc1 = (const float*)d_in[12];
  const float* bc1 = (const float*)d_in[13];
  const float* Wc2 = (const float*)d_in[14];
  const float* bc2 = (const float*)d_in[15];
  float* out = (float*)d_out;

  // workspace layout (~130 MB)
  _Float16* C    = (_Float16*)d_ws;                  // 32000*528
  _Float16* WsT2 = C + (size_t)32000 * NW;           // 540672
  _Float16* XH   = WsT2 + 540672;                    // 32000*1024
  _Float16* Zh   = XH + (size_t)32000 * 1024;        // 32000*256
  float* Ss   = (float*)(Zh + (size_t)32000 * 256);  // 32000*8
  float* Xp   = Ss + 256000;                         // 32*8*256
  float* Ap   = Xp + 65536;                          // 32*64
  float* Hacc = Ap + 2048;                           // 32*256
  int* deg     = (int*)(Hacc + 8192);                // 32000
  int* cursor  = deg + 32000;                        // 32000
  int* offsets = cursor + 32000;                     // 32001
  int* srcS    = offsets + 32001;                    // 256000
  unsigned* zbuf = (unsigned*)Xp;                    // Xp+Ap+Hacc = 75776 words

  const int* src = ei;
  const int* dst = ei + N_EDGES;

  hipMemsetAsync(deg, 0, 64000 * sizeof(int), stream);   // deg + cursor
  prep_all<<<16512, 256, 0, stream>>>(Wl1, Wr1, Wla, Wra, x, WsT2, XH, zbuf, dst, deg);
  gemm_mfma<<<1251, 256, 0, stream>>>(XH, WsT2, C, deg, offsets);
  scatter_kernel<<<1000, 256, 0, stream>>>(src, dst, offsets, cursor, srcS);
  aggregate_node<<<8000, 256, 0, stream>>>(C, offsets, srcS, bl1, bla, Zh, Ss);
  pool_kernel<<<256, 256, 0, stream>>>(Ss, Zh, offsets, srcS, Xp, Ap);
  zpcls_kernel<<<256, 256, 0, stream>>>(Xp, Ap, Wl2, bl2, Wr2, Wc1, Hacc);
  out_kernel<<<32, 256, 0, stream>>>(Hacc, bc1, Wc2, bc2, out);
}

// Round 22
// 192.965 us; speedup vs baseline: 1.0713x; 1.0713x over previous
//
#include <hip/hip_runtime.h>
#include <hip/hip_bf16.h>
#include <math.h>

#define N_NODES 32000
#define NUM_GRAPHS 32
#define NPG 1000
#define N_EDGES 256000
#define IN_DIM 1024
#define HID 256
#define NW 528    // C width: 256 (Wl1) + 256 (Wr1) + 8 (Wla) + 8 (Wra)
#define KBH 1040  // B LDS halves-stride per kb-block: 128*8 + 16 pad (2080 B)
#define AFB 520   // A LDS float-stride per koct-block: 64*8 + 8 pad (2080 B)
#define WS_KS 33792  // WsT2 halves per K=64 step: 4*8192 + 1024
#define ZWORDS 75776 // prep-zeroed scratch: Xp 65536 + Ap 2048 + Hacc 8192 (deg/cursor via memset)

typedef _Float16 half8 __attribute__((ext_vector_type(8)));
typedef _Float16 half4 __attribute__((ext_vector_type(4)));
typedef float f32x4 __attribute__((ext_vector_type(4)));

__device__ __forceinline__ void gload16(const void* g, void* l) {
  __builtin_amdgcn_global_load_lds((const __attribute__((address_space(1))) void*)g,
                                   (__attribute__((address_space(3))) void*)l, 16, 0, 0);
}

// ---------------- prep: zero Xp/Ap/Hacc + W-convert (BK=64 chunk order) + count_deg ----------------
// grid (4,128). bx<3: W-convert (n = bx*256+t, kslot = by). bx==3: 128 blocks count edges.
// Per K=64 step ks (16): nb<4 tiles of 1024 chunks (c = kb*128 + col, kb = k-octet 0..7)
// at ks*WS_KS + nb*8192 + c*8; SP cols at ks*WS_KS + 32768 + (kb*16 + ns)*8.
__global__ __launch_bounds__(256) void prep_kernel(
    const float* __restrict__ Wl1, const float* __restrict__ Wr1,
    const float* __restrict__ Wla, const float* __restrict__ Wra,
    _Float16* __restrict__ WsT2, unsigned* __restrict__ zbuf,
    const int* __restrict__ dst, int* __restrict__ deg)
{
  const int t = threadIdx.x;
  const int bx = blockIdx.x, by = blockIdx.y;
  const int flat = by * 4 + bx;   // 0..511
  for (int i = flat * 256 + t; i < ZWORDS; i += 512 * 256) zbuf[i] = 0u;

  if (bx == 3) {
    const int e0 = by * 2000;
    for (int i = t; i < 2000; i += 256) atomicAdd(&deg[dst[e0 + i]], 1);
    return;
  }

  const int kslot = by;                // 0..127 -> k0 = kslot*8
  const int n = bx * 256 + t;
  if (n >= NW) return;
  const int k0 = kslot * 8;
  half8 o;
#pragma unroll
  for (int i = 0; i < 8; ++i) {
    const int k = k0 + i;
    float v;
    if (n < 256)      v = Wl1[(size_t)k * 256 + n];
    else if (n < 512) v = Wr1[(size_t)k * 256 + n - 256];
    else if (n < 520) v = Wla[(size_t)k * 8 + n - 512];
    else              v = Wra[(size_t)k * 8 + n - 520];
    o[i] = (_Float16)v;
  }
  const int ks = kslot >> 3, kb = kslot & 7;
  size_t off;
  if (n < 512) off = (size_t)ks * WS_KS + (size_t)(n >> 7) * 8192 + (kb * 128 + (n & 127)) * 8;
  else         off = (size_t)ks * WS_KS + 32768 + (kb * 16 + (n - 512)) * 8;
  *(half8*)&WsT2[off] = o;
}

// ---------------- MFMA GEMM + embedded scan block ----------------
// Blocks 0..2499: C[32000,528](fp16) = fp16(x) @ fp16([Wl1|Wr1|Wla|Wra]).
// BM=64, BN=128, BK=64 (16 K-steps). A staged raw f32 (8 koct-blocks), cvt at frag load.
// Block 2500: CSR prefix scan (deg -> offsets), hidden under the gemm.
__global__ __launch_bounds__(256) void gemm_mfma(
    const float* __restrict__ x, const _Float16* __restrict__ WsT2,
    _Float16* __restrict__ C, const int* __restrict__ deg, int* __restrict__ offsets)
{
  __shared__ float    AF[8 * AFB];   // 8 koct-blocks: 64 rows x 8 f32 (+8 pad)
  __shared__ _Float16 Bs[8 * KBH];   // 8 kb-blocks: 128 cols x 8 fp16 (+16 pad)

  const int orig = blockIdx.x;
  const int tid = threadIdx.x;

  if (orig == 2500) {
    // ---- scan block: 256 threads x 125 nodes, two-pass ----
    int* part = (int*)AF;
    const int base = tid * 125;
    int s = 0;
    for (int i = 0; i < 125; ++i) s += deg[base + i];
    part[tid] = s;
    __syncthreads();
    for (int off = 1; off < 256; off <<= 1) {
      int v = (tid >= off) ? part[tid - off] : 0;
      __syncthreads();
      part[tid] += v;
      __syncthreads();
    }
    int run = part[tid] - s;   // exclusive prefix
    for (int i = 0; i < 125; ++i) {
      offsets[base + i] = run;
      run += deg[base + i];
    }
    if (tid == 255) offsets[N_NODES] = part[255];
    return;
  }

  const int xcd = orig & 7, idx = orig >> 3;
  // bijective XCD swizzle, nwg=2500: q=312, r=4
  const int g = (xcd < 4 ? xcd * 313 : 1252 + (xcd - 4) * 312) + idx;
  const int pm = g / 5, nb = g % 5;
  const int m0 = pm * 64;

  const int w = tid >> 6, l = tid & 63;
  const int wr = w >> 1, wc = w & 1;
  const int r16 = l & 15, kb4 = l >> 4;

  // A staging: 4 chunks/thread. c = tid + j*256 (0..1023): koct = c>>7, rem = c&127
  // (row = rem>>1, half = rem&1). Wave-uniform koct per 64-chunk run.
  int lpAf[4];
  const float* gA[4];
#pragma unroll
  for (int j = 0; j < 4; ++j) {
    const int c = tid + j * 256;
    const int koct = c >> 7, rem = c & 127;
    lpAf[j] = koct * AFB + rem * 4;
    gA[j] = x + (size_t)(m0 + (rem >> 1)) * IN_DIM + koct * 8 + (rem & 1) * 4;
  }
  // B staging: 4 chunks/thread. c = tid + j*256: kb = c>>7 (0..7), col = c&127.
  int lpB[4];
  const _Float16* gB[4];
#pragma unroll
  for (int j = 0; j < 4; ++j) {
    const int c = tid + j * 256;
    const int kb = c >> 7, col = c & 127;
    lpB[j] = kb * KBH + col * 8;
    gB[j] = WsT2 + nb * 8192 + (size_t)c * 8;   // valid for nb<4 (chunk order = kb*128+col)
  }

  if (nb < 4) {
    f32x4 acc[2][4] = {};
    for (int ks = 0; ks < 16; ++ks) {
      const size_t ko = (size_t)ks * 64;        // floats
      const size_t bo = (size_t)ks * WS_KS;     // halves
      __syncthreads();
#pragma unroll
      for (int j = 0; j < 4; ++j) {
        gload16(gA[j] + ko, &AF[lpAf[j]]);
        gload16(gB[j] + bo, &Bs[lpB[j]]);
      }
      __syncthreads();

#pragma unroll
      for (int s = 0; s < 2; ++s) {
        const int kblk = s * 4 + kb4;
        half8 bf[4];
#pragma unroll
        for (int n = 0; n < 4; ++n)
          bf[n] = *(half8*)&Bs[kblk * KBH + (wc * 64 + n * 16 + r16) * 8];
#pragma unroll
        for (int m = 0; m < 2; ++m) {
          const float* ap = &AF[kblk * AFB + (wr * 32 + m * 16 + r16) * 8];
          float fa[8];
          *(f32x4*)&fa[0] = *(const f32x4*)ap;
          *(f32x4*)&fa[4] = *(const f32x4*)(ap + 4);
          half8 ah;
#pragma unroll
          for (int i = 0; i < 8; ++i) ah[i] = (_Float16)fa[i];
#pragma unroll
          for (int n = 0; n < 4; ++n)
            acc[m][n] = __builtin_amdgcn_mfma_f32_16x16x32_f16(ah, bf[n], acc[m][n], 0, 0, 0);
        }
      }
    }

    const int crow0 = m0 + wr * 32 + ((l >> 4) << 2);
    const int ccol0 = nb * 128 + wc * 64 + r16;
#pragma unroll
    for (int m = 0; m < 2; ++m)
#pragma unroll
      for (int n = 0; n < 4; ++n)
#pragma unroll
        for (int r = 0; r < 4; ++r)
          C[(size_t)(crow0 + m * 16 + r) * NW + ccol0 + n * 16] = (_Float16)acc[m][n][r];
  } else {
    // SP block: 16 cols (512..527); B tile = 128 chunks (tid<128), linear LDS chunk order
    f32x4 acc2 = {};
    for (int ks = 0; ks < 16; ++ks) {
      const size_t ko = (size_t)ks * 64;
      const size_t bo = (size_t)ks * WS_KS + 32768;
      __syncthreads();
#pragma unroll
      for (int j = 0; j < 4; ++j) gload16(gA[j] + ko, &AF[lpAf[j]]);
      if (tid < 128) gload16(WsT2 + bo + tid * 8, &Bs[tid * 8]);
      __syncthreads();

#pragma unroll
      for (int s = 0; s < 2; ++s) {
        const int kblk = s * 4 + kb4;
        half8 bfs = *(half8*)&Bs[(kblk * 16 + r16) * 8];
        const float* ap = &AF[kblk * AFB + (w * 16 + r16) * 8];
        float fa[8];
        *(f32x4*)&fa[0] = *(const f32x4*)ap;
        *(f32x4*)&fa[4] = *(const f32x4*)(ap + 4);
        half8 ah;
#pragma unroll
        for (int i = 0; i < 8; ++i) ah[i] = (_Float16)fa[i];
        acc2 = __builtin_amdgcn_mfma_f32_16x16x32_f16(ah, bfs, acc2, 0, 0, 0);
      }
    }
    const int crow0 = m0 + w * 16 + ((l >> 4) << 2);
    const int ccol0 = 512 + r16;
#pragma unroll
    for (int r = 0; r < 4; ++r)
      C[(size_t)(crow0 + r) * NW + ccol0] = (_Float16)acc2[r];
  }
}

__global__ void scatter_kernel(const int* __restrict__ src, const int* __restrict__ dst,
                               const int* __restrict__ offsets, int* __restrict__ cursor,
                               int* __restrict__ srcSorted) {
  int e = blockIdx.x * blockDim.x + threadIdx.x;
  if (e < N_EDGES) {
    int d = dst[e];
    int pos = offsets[d] + atomicAdd(&cursor[d], 1);
    srcSorted[pos] = src[e];
  }
}

// ---------------- per-node aggregation: wave-per-node, vectorized gathers ----------------
__global__ __launch_bounds__(256) void aggregate_node(
    const _Float16* __restrict__ C,
    const int* __restrict__ offsets, const int* __restrict__ srcSorted,
    const float* __restrict__ bl1, const float* __restrict__ bla,
    _Float16* __restrict__ Zh, float* __restrict__ Ss)
{
  const int bid = blockIdx.x;
  const int wv = threadIdx.x >> 6, lane = threadIdx.x & 63;
  const int node = (bid & 7) * 4000 + (bid >> 3) * 4 + wv;  // graphs pinned to XCDs
  const int b = offsets[node], e = offsets[node + 1];
  const int cnt = e - b;
  const float4 blv = *(const float4*)(bl1 + 4 * lane);
  float a0 = 0.f, a1 = 0.f, a2 = 0.f, a3 = 0.f, sp = 0.f;
  int p = b;
  int sNext = (p < e) ? srcSorted[p] : 0;
  while (p < e) {
    const int s = sNext;
    ++p;
    sNext = (p < e) ? srcSorted[p] : 0;   // prefetch next index
    const _Float16* row = C + (size_t)s * NW;
    half4 v = *(const half4*)(row + 4 * lane);
    float spv = 0.f;
    if (lane < 8) spv = (float)row[512 + lane];
    a0 += (float)v[0]; a1 += (float)v[1]; a2 += (float)v[2]; a3 += (float)v[3];
    sp += spv;
  }
  const float inv = (cnt > 0) ? 1.f / (float)cnt : 0.f;
  const _Float16* self = C + (size_t)node * NW;
  half4 sv = *(const half4*)(self + 256 + 4 * lane);
  half4 zo;
  zo[0] = (_Float16)fmaxf(a0 * inv + blv.x + (float)sv[0], 0.f);
  zo[1] = (_Float16)fmaxf(a1 * inv + blv.y + (float)sv[1], 0.f);
  zo[2] = (_Float16)fmaxf(a2 * inv + blv.z + (float)sv[2], 0.f);
  zo[3] = (_Float16)fmaxf(a3 * inv + blv.w + (float)sv[3], 0.f);
  *(half4*)(Zh + (size_t)node * 256 + 4 * lane) = zo;

  float sval = 0.f;
  if (lane < 8) sval = sp * inv + bla[lane] + (float)self[520 + lane];
  float m = sval;
  m = fmaxf(m, __shfl_xor(m, 1));
  m = fmaxf(m, __shfl_xor(m, 2));
  m = fmaxf(m, __shfl_xor(m, 4));
  float ex = expf(sval - m);
  float su = ex;
  su += __shfl_xor(su, 1);
  su += __shfl_xor(su, 2);
  su += __shfl_xor(su, 4);
  if (lane < 8) Ss[(size_t)node * 8 + lane] = ex / su;
}

// ---------------- pool: per 125-node chunk: AggS (LDS) -> Ap partial + Xp partial ----------------
__global__ __launch_bounds__(256) void pool_kernel(
    const float* __restrict__ Ss, const _Float16* __restrict__ Zh,
    const int* __restrict__ offsets, const int* __restrict__ srcSorted,
    float* __restrict__ Xp, float* __restrict__ Ap)
{
  const int g = blockIdx.x >> 3;
  const int chunk = blockIdx.x & 7;
  const int n0 = g * NPG + chunk * 125;
  const int t = threadIdx.x;
  __shared__ float lSs[125][8];
  __shared__ float lAg[125][8];
  __shared__ float apTmp[4][64];

  if (t < 125) {
    const int node = n0 + t;
    float4 s0 = *(const float4*)&Ss[(size_t)node * 8];
    float4 s1 = *(const float4*)&Ss[(size_t)node * 8 + 4];
    lSs[t][0] = s0.x; lSs[t][1] = s0.y; lSs[t][2] = s0.z; lSs[t][3] = s0.w;
    lSs[t][4] = s1.x; lSs[t][5] = s1.y; lSs[t][6] = s1.z; lSs[t][7] = s1.w;
    float a[8] = {0.f, 0.f, 0.f, 0.f, 0.f, 0.f, 0.f, 0.f};
    const int b = offsets[node], e = offsets[node + 1];
    for (int p = b; p < e; ++p) {
      const int s = srcSorted[p];
      float4 v0 = *(const float4*)&Ss[(size_t)s * 8];
      float4 v1 = *(const float4*)&Ss[(size_t)s * 8 + 4];
      a[0] += v0.x; a[1] += v0.y; a[2] += v0.z; a[3] += v0.w;
      a[4] += v1.x; a[5] += v1.y; a[6] += v1.z; a[7] += v1.w;
    }
#pragma unroll
    for (int c = 0; c < 8; ++c) lAg[t][c] = a[c];
  }
  __syncthreads();
  {
    const int sl = t >> 6, i = (t >> 3) & 7, j = t & 7;
    float acc = 0.f;
    for (int n = sl; n < 125; n += 4) acc += lAg[n][i] * lSs[n][j];
    apTmp[sl][((i << 3) | j)] = acc;
  }
  __syncthreads();
  if (t < 64) atomicAdd(&Ap[g * 64 + t], apTmp[0][t] + apTmp[1][t] + apTmp[2][t] + apTmp[3][t]);
  float xc[8] = {0.f, 0.f, 0.f, 0.f, 0.f, 0.f, 0.f, 0.f};
  for (int n = 0; n < 125; ++n) {
    float zv = (float)Zh[(size_t)(n0 + n) * 256 + t];
#pragma unroll
    for (int c = 0; c < 8; ++c) xc[c] = fmaf(lSs[n][c], zv, xc[c]);
  }
#pragma unroll
  for (int c = 0; c < 8; ++c)
    atomicAdd(&Xp[((size_t)g * 8 + c) * 256 + t], xc[c]);
}

// ---------------- zpcls: per (g,j) pooled node: agg -> Zp row -> Wc1 partial -> Hacc ----------------
__global__ __launch_bounds__(256) void zpcls_kernel(
    const float* __restrict__ Xp, const float* __restrict__ Ap,
    const float* __restrict__ Wl2, const float* __restrict__ bl2,
    const float* __restrict__ Wr2, const float* __restrict__ Wc1,
    float* __restrict__ Hacc)
{
  const int g = blockIdx.x >> 3;
  const int j = blockIdx.x & 7;
  const int c = threadIdx.x;
  __shared__ float lXp[8][256];
  __shared__ float agg[256];
  __shared__ float zrow[256];
  __shared__ float lAp[64];
#pragma unroll
  for (int i = 0; i < 8; ++i) lXp[i][c] = Xp[((size_t)g * 8 + i) * 256 + c];
  if (c < 64) lAp[c] = Ap[g * 64 + c];
  __syncthreads();
  {
    float d = 0.f, s = 0.f;
#pragma unroll
    for (int i = 0; i < 8; ++i) {
      bool m = (lAp[i * 8 + j] != 0.f);
      d += m ? 1.f : 0.f;
      s += m ? lXp[i][c] : 0.f;
    }
    agg[c] = (d > 0.f) ? s / fmaxf(d, 1.f) : 0.f;
  }
  __syncthreads();
  float az = bl2[c];
#pragma unroll 8
  for (int k = 0; k < 256; ++k)
    az += agg[k] * Wl2[(size_t)k * 256 + c] + lXp[j][k] * Wr2[(size_t)k * 256 + c];
  zrow[c] = fmaxf(az, 0.f);
  __syncthreads();
  float h = 0.f;
  const float* wc1 = Wc1 + (size_t)(j * 256) * 256 + c;
#pragma unroll 8
  for (int k = 0; k < 256; ++k)
    h = fmaf(zrow[k], wc1[(size_t)k * 256], h);
  atomicAdd(&Hacc[g * 256 + c], h);
}

// ---------------- out: out[g] = bc2 + sum_c relu(Hacc+bc1)*Wc2 ----------------
__global__ __launch_bounds__(256) void out_kernel(
    const float* __restrict__ Hacc, const float* __restrict__ bc1,
    const float* __restrict__ Wc2, const float* __restrict__ bc2,
    float* __restrict__ out)
{
  const int g = blockIdx.x;
  const int t = threadIdx.x;
  __shared__ float red[256];
  red[t] = fmaxf(Hacc[g * 256 + t] + bc1[t], 0.f) * Wc2[t];
  __syncthreads();
  for (int off = 128; off > 0; off >>= 1) {
    if (t < off) red[t] += red[t + off];
    __syncthreads();
  }
  if (t == 0) out[g] = red[0] + bc2[0];
}

extern "C" void kernel_launch(void* const* d_in, const int* in_sizes, int n_in,
                              void* d_out, int out_size, void* d_ws, size_t ws_size,
                              hipStream_t stream) {
  const float* x   = (const float*)d_in[0];
  const int*   ei  = (const int*)d_in[1];
  const float* Wl1 = (const float*)d_in[3];
  const float* bl1 = (const float*)d_in[4];
  const float* Wr1 = (const float*)d_in[5];
  const float* Wla = (const float*)d_in[6];
  const float* bla = (const float*)d_in[7];
  const float* Wra = (const float*)d_in[8];
  const float* Wl2 = (const float*)d_in[9];
  const float* bl2 = (const float*)d_in[10];
  const float* Wr2 = (const float*)d_in[11];
  const float* Wc1 = (const float*)d_in[12];
  const float* bc1 = (const float*)d_in[13];
  const float* Wc2 = (const float*)d_in[14];
  const float* bc2 = (const float*)d_in[15];
  float* out = (float*)d_out;

  // workspace layout (~65 MB)
  _Float16* C    = (_Float16*)d_ws;                  // 32000*528
  _Float16* WsT2 = C + (size_t)32000 * NW;           // 540672
  _Float16* Zh   = WsT2 + 540672;                    // 32000*256
  float* Ss   = (float*)(Zh + (size_t)32000 * 256);  // 32000*8
  float* Xp   = Ss + 256000;                         // 32*8*256
  float* Ap   = Xp + 65536;                          // 32*64
  float* Hacc = Ap + 2048;                           // 32*256
  int* deg     = (int*)(Hacc + 8192);                // 32000
  int* cursor  = deg + 32000;                        // 32000
  int* offsets = cursor + 32000;                     // 32001
  int* srcS    = offsets + 32001;                    // 256000
  unsigned* zbuf = (unsigned*)Xp;                    // Xp+Ap+Hacc = 75776 words

  const int* src = ei;
  const int* dst = ei + N_EDGES;

  hipMemsetAsync(deg, 0, 64000 * sizeof(int), stream);   // deg + cursor
  prep_kernel<<<dim3(4, 128), 256, 0, stream>>>(Wl1, Wr1, Wla, Wra, WsT2, zbuf, dst, deg);
  gemm_mfma<<<2501, 256, 0, stream>>>(x, WsT2, C, deg, offsets);
  scatter_kernel<<<1000, 256, 0, stream>>>(src, dst, offsets, cursor, srcS);
  aggregate_node<<<8000, 256, 0, stream>>>(C, offsets, srcS, bl1, bla, Zh, Ss);
  pool_kernel<<<256, 256, 0, stream>>>(Ss, Zh, offsets, srcS, Xp, Ap);
  zpcls_kernel<<<256, 256, 0, stream>>>(Xp, Ap, Wl2, bl2, Wr2, Wc1, Hacc);
  out_kernel<<<32, 256, 0, stream>>>(Hacc, bc1, Wc2, bc2, out);
}